// Round 4
// baseline (4234.887 us; speedup 1.0000x reference)
//
#include <hip/hip_runtime.h>
#include <hip/hip_bf16.h>
#include <math.h>

#define NN 50000
#define TT 12
#define FF 32
#define HH 64

static inline size_t align256(size_t x){ return (x + 255) & ~(size_t)255; }

// ---------------- graph preprocessing ----------------

__global__ void k_count(const int* __restrict__ dst, int E, int* __restrict__ cnt){
  int i = blockIdx.x*blockDim.x + threadIdx.x;
  if (i < E) atomicAdd(&cnt[dst[i]], 1);
}

__global__ void k_dinv(const int* __restrict__ cnt, float* __restrict__ dinv,
                       float* __restrict__ invd, int n){
  int i = blockIdx.x*blockDim.x + threadIdx.x;
  if (i < n){
    float d = (float)(cnt[i] + 1);            // +1 self loop
    dinv[i] = (float)(1.0 / sqrt((double)d));
    invd[i] = 1.0f / d;
  }
}

#define SCAN_T 256
__global__ void k_scan(const int* __restrict__ cnt, int* __restrict__ rp, int n){
  __shared__ int s[SCAN_T];
  int t = threadIdx.x;
  int chunk = (n + SCAN_T - 1) / SCAN_T;
  int lo = t*chunk, hi = min(lo+chunk, n);
  int sum = 0;
  for (int i = lo; i < hi; ++i) sum += cnt[i];
  s[t] = sum; __syncthreads();
  for (int off = 1; off < SCAN_T; off <<= 1){
    int v = (t >= off) ? s[t-off] : 0;
    __syncthreads();
    s[t] += v;
    __syncthreads();
  }
  int run = (t == 0) ? 0 : s[t-1];
  for (int i = lo; i < hi; ++i){ rp[i] = run; run += cnt[i]; }
  if (t == SCAN_T-1) rp[n] = run;
}

__global__ void k_fill(const int* __restrict__ src, const int* __restrict__ dst, int E,
                       const int* __restrict__ rp, int* __restrict__ cur,
                       const float* __restrict__ dinv,
                       int* __restrict__ es, float* __restrict__ en){
  int i = blockIdx.x*blockDim.x + threadIdx.x;
  if (i < E){
    int d = dst[i], s = src[i];
    int pos = rp[d] + atomicAdd(&cur[d], 1);
    es[pos] = s;
    en[pos] = dinv[s] * dinv[d];
  }
}

// ---------------- aggregation (SpMM), single timestep ----------------
// xt: [N,32]. Half-wave (32 lanes) per node; lane&31 = feature.
__global__ void k_agg_x(const float* __restrict__ xt, const int* __restrict__ rp,
                        const int* __restrict__ es, const float* __restrict__ en,
                        const float* __restrict__ invd, float* __restrict__ out){
  int n = (blockIdx.x*blockDim.x + threadIdx.x) >> 5;
  if (n >= NN) return;
  int f = threadIdx.x & 31;
  float acc = invd[n] * xt[(size_t)n*FF + f];
  int e = rp[n], e1 = rp[n+1];
  for (; e + 4 <= e1; e += 4){
    int   s0 = es[e],   s1 = es[e+1], s2 = es[e+2], s3 = es[e+3];
    float w0 = en[e],   w1 = en[e+1], w2 = en[e+2], w3 = en[e+3];
    float v0 = xt[(size_t)s0*FF + f];
    float v1 = xt[(size_t)s1*FF + f];
    float v2 = xt[(size_t)s2*FF + f];
    float v3 = xt[(size_t)s3*FF + f];
    acc += w0*v0; acc += w1*v1; acc += w2*v2; acc += w3*v3;
  }
  for (; e < e1; ++e) acc += en[e] * xt[(size_t)es[e]*FF + f];
  out[(size_t)n*FF + f] = acc;
}

// h: [N,64]. Wave per node; lane = feature.
__global__ void k_agg_h(const float* __restrict__ h, const int* __restrict__ rp,
                        const int* __restrict__ es, const float* __restrict__ en,
                        const float* __restrict__ invd, float* __restrict__ out){
  int n = blockIdx.x*(blockDim.x >> 6) + (threadIdx.x >> 6);
  if (n >= NN) return;
  int lane = threadIdx.x & 63;
  float acc = invd[n] * h[(size_t)n*HH + lane];
  int e = rp[n], e1 = rp[n+1];
  for (; e + 4 <= e1; e += 4){
    int   s0 = es[e],   s1 = es[e+1], s2 = es[e+2], s3 = es[e+3];
    float w0 = en[e],   w1 = en[e+1], w2 = en[e+2], w3 = en[e+3];
    float v0 = h[(size_t)s0*HH + lane];
    float v1 = h[(size_t)s1*HH + lane];
    float v2 = h[(size_t)s2*HH + lane];
    float v3 = h[(size_t)s3*HH + lane];
    acc += w0*v0; acc += w1*v1; acc += w2*v2; acc += w3*v3;
  }
  for (; e < e1; ++e) acc += en[e] * h[(size_t)es[e]*HH + lane];
  out[(size_t)n*HH + lane] = acc;
}

// ---------------- GEMM: C[M,64] = act(A[M,K] @ W[K,64] + bias) --------------
template<int K, int ROWS, bool RELU>
__launch_bounds__(64)
__global__ void k_gemm(const float* __restrict__ A, const float* __restrict__ W,
                       const float* __restrict__ bias, float* __restrict__ C,
                       int M){
  int col = threadIdx.x;
  float w[K];
  #pragma unroll
  for (int k = 0; k < K; ++k) w[k] = W[(size_t)k*HH + col];
  float b = bias[col];
  int row0 = blockIdx.x*ROWS;
  if (row0 >= M) return;
  float acc[ROWS];
  #pragma unroll
  for (int r = 0; r < ROWS; ++r) acc[r] = b;
  #pragma unroll
  for (int r = 0; r < ROWS; ++r){
    const float* ar = A + (size_t)(row0 + r)*K;
    #pragma unroll
    for (int k = 0; k < K; ++k)
      acc[r] = fmaf(ar[k], w[k], acc[r]);
  }
  #pragma unroll
  for (int r = 0; r < ROWS; ++r){
    float v = acc[r];
    if (RELU) v = fmaxf(v, 0.f);
    C[(size_t)(row0 + r)*HH + col] = v;
  }
}

// ---------------- fused GRU step -------------------------------------------
// lane = node; 4 waves/block each own 16 output cols j. Weights wave-uniform.
__launch_bounds__(256)
__global__ void k_gru(const float* __restrict__ h2, const float* __restrict__ hprev,
                      const float* __restrict__ Wih, const float* __restrict__ Whh,
                      const float* __restrict__ bih, const float* __restrict__ bhh,
                      float* __restrict__ hnew){
  int lane  = threadIdx.x & 63;
  int jbase = __builtin_amdgcn_readfirstlane((threadIdx.x >> 6) << 4);
  int n = blockIdx.x*64 + lane;
  bool ok = (n < NN);
  int nc = ok ? n : NN-1;
  const float* h2r = h2    + (size_t)nc*HH;
  const float* hpr = hprev + (size_t)nc*HH;
  float a[HH], b[HH];
  #pragma unroll
  for (int k = 0; k < HH; ++k){ a[k] = h2r[k]; b[k] = hpr[k]; }
  for (int jj = 0; jj < 16; ++jj){
    int j = jbase + jj;
    const float* wir = Wih + (size_t)j*HH;
    const float* whr = Whh + (size_t)j*HH;
    float ir = bih[j], iz = bih[j+64], in_ = bih[j+128];
    float hr = bhh[j], hz = bhh[j+64], hn  = bhh[j+128];
    #pragma unroll
    for (int k = 0; k < HH; ++k){
      float ak = a[k], bk = b[k];
      ir  = fmaf(ak, wir[k],          ir);
      iz  = fmaf(ak, wir[64*HH + k],  iz);
      in_ = fmaf(ak, wir[128*HH + k], in_);
      hr  = fmaf(bk, whr[k],          hr);
      hz  = fmaf(bk, whr[64*HH + k],  hz);
      hn  = fmaf(bk, whr[128*HH + k], hn);
    }
    float r  = 1.f/(1.f + expf(-(ir + hr)));
    float z  = 1.f/(1.f + expf(-(iz + hz)));
    float nv = tanhf(in_ + r*hn);
    float hp = hpr[j];                    // L1 hit; avoids runtime reg-index
    if (ok) hnew[(size_t)n*HH + j] = (1.f - z)*nv + z*hp;
  }
}

// ---------------- head: logits = relu(h@Wc1+bc1)@Wc2 + bc2 ----------------
__global__ void k_head(const float* __restrict__ h, const float* __restrict__ Wc1,
                       const float* __restrict__ bc1, const float* __restrict__ Wc2,
                       const float* __restrict__ bc2, float* __restrict__ out){
  __shared__ float w1[64*32];
  __shared__ float w2[32];
  for (int i = threadIdx.x; i < 64*32; i += blockDim.x) w1[i] = Wc1[i];
  if (threadIdx.x < 32) w2[threadIdx.x] = Wc2[threadIdx.x];
  __syncthreads();
  int n = blockIdx.x*blockDim.x + threadIdx.x;
  if (n >= NN) return;
  const float* hr = h + (size_t)n*64;
  float hreg[64];
  #pragma unroll
  for (int k = 0; k < 64; ++k) hreg[k] = hr[k];
  float acc2 = bc2[0];
  #pragma unroll
  for (int c = 0; c < 32; ++c){
    float a = bc1[c];
    #pragma unroll
    for (int k = 0; k < 64; ++k) a = fmaf(hreg[k], w1[k*32 + c], a);
    a = fmaxf(a, 0.f);
    acc2 = fmaf(a, w2[c], acc2);
  }
  out[n] = acc2;
}

// ---------------- launch ----------------
extern "C" void kernel_launch(void* const* d_in, const int* in_sizes, int n_in,
                              void* d_out, int out_size, void* d_ws, size_t ws_size,
                              hipStream_t stream){
  const float* x    = (const float*)d_in[0];
  const int*   ei   = (const int*)  d_in[1];
  const float* W1   = (const float*)d_in[2];
  const float* b1   = (const float*)d_in[3];
  const float* W2   = (const float*)d_in[4];
  const float* b2   = (const float*)d_in[5];
  const float* W_ih = (const float*)d_in[6];
  const float* W_hh = (const float*)d_in[7];
  const float* b_ih = (const float*)d_in[8];
  const float* b_hh = (const float*)d_in[9];
  const float* Wc1  = (const float*)d_in[10];
  const float* bc1  = (const float*)d_in[11];
  const float* Wc2  = (const float*)d_in[12];
  const float* bc2  = (const float*)d_in[13];
  int E = in_sizes[1] / 2;
  const int* src = ei;
  const int* dst = ei + E;

  char* w = (char*)d_ws;
  auto alloc = [&](size_t bytes){ char* p = w; w += align256(bytes); return p; };
  int*   cnt  = (int*)  alloc((size_t)NN*4);
  int*   rp   = (int*)  alloc((size_t)(NN+1)*4);
  int*   cur  = (int*)  alloc((size_t)NN*4);
  float* dinv = (float*)alloc((size_t)NN*4);
  float* invd = (float*)alloc((size_t)NN*4);
  int*   es   = (int*)  alloc((size_t)E*4);
  float* en   = (float*)alloc((size_t)E*4);
  float* U1   = (float*)alloc((size_t)NN*HH*4);   // aggX [N,32] / agg2 [N,64]
  float* U2   = (float*)alloc((size_t)NN*HH*4);   // h1 / h2  [N,64]
  float* hA   = (float*)alloc((size_t)NN*HH*4);
  float* hB   = (float*)alloc((size_t)NN*HH*4);
  // ~65 MB total. If workspace can't hold it, fail CLEANLY (stub-level absmax)
  // instead of faulting the device: diagnostic for next round.
  if ((size_t)(w - (char*)d_ws) > ws_size) return;

  hipMemsetAsync(cnt, 0, (size_t)NN*4, stream);
  hipMemsetAsync(cur, 0, (size_t)NN*4, stream);
  hipMemsetAsync(hA,  0, (size_t)NN*HH*4, stream);   // h0 = 0

  k_count<<<(E+255)/256, 256, 0, stream>>>(dst, E, cnt);
  k_dinv <<<(NN+255)/256, 256, 0, stream>>>(cnt, dinv, invd, NN);
  k_scan <<<1, SCAN_T, 0, stream>>>(cnt, rp, NN);
  k_fill <<<(E+255)/256, 256, 0, stream>>>(src, dst, E, rp, cur, dinv, es, en);

  float* hprev = hA;
  float* hnext = hB;
  for (int t = 0; t < TT; ++t){
    const float* xt = x + (size_t)t*NN*FF;
    // layer 1: aggregate x first ((A X) W == A (X W)), then GEMM 32->64 + relu
    k_agg_x<<<(NN*32 + 255)/256, 256, 0, stream>>>(xt, rp, es, en, invd, U1);
    k_gemm<FF, 16, true><<<(NN + 15)/16, 64, 0, stream>>>(U1, W1, b1, U2, NN);
    // layer 2
    k_agg_h<<<(NN + 3)/4, 256, 0, stream>>>(U2, rp, es, en, invd, U1);
    k_gemm<HH, 16, true><<<(NN + 15)/16, 64, 0, stream>>>(U1, W2, b2, U2, NN);
    // GRU step consuming h2
    k_gru<<<(NN + 63)/64, 256, 0, stream>>>(U2, hprev, W_ih, W_hh, b_ih, b_hh, hnext);
    float* tmp = hprev; hprev = hnext; hnext = tmp;
  }

  // after 12 swaps hprev == hA
  k_head<<<(NN + 255)/256, 256, 0, stream>>>(hprev, Wc1, bc1, Wc2, bc2, (float*)d_out);
}